// Round 18
// baseline (557.312 us; speedup 1.0000x reference)
//
#include <hip/hip_runtime.h>
#include <cstdint>
#include <cstddef>

typedef float  f32x4  __attribute__((ext_vector_type(4)));
typedef short  bf16x8 __attribute__((ext_vector_type(8)));
typedef unsigned short u16;
typedef u16    u16x8  __attribute__((ext_vector_type(8)));
typedef unsigned int u32;

#define T_SEQ 2048
#define N_HEADS 32
#define N_KVH 8
#define HD 128
#define QSCALE 0.12751743648963412f   // 1/sqrt(128) * log2(e)

__device__ __forceinline__ u16 f2bf(float f){
  union { float f; unsigned u; } v; v.f = f;
  unsigned u = v.u;
  u += 0x7fffu + ((u >> 16) & 1u);   // RNE truncate
  return (u16)(u >> 16);
}

__device__ __forceinline__ u32 cvt_pk_bf16(float a, float b){
  u32 r;
  asm volatile("v_cvt_pk_bf16_f32 %0, %1, %2" : "=v"(r) : "v"(a), "v"(b));
  return r;  // low16 = bf16(a), high16 = bf16(b)
}

__device__ __forceinline__ void gll16(const void* g, void* l){
  __builtin_amdgcn_global_load_lds((const __attribute__((address_space(1))) void*)g,
                                   (__attribute__((address_space(3))) void*)l, 16, 0, 0);
}

// ---------------- cos/sin tables from freqs (T x 64), plus transposed (64 x T) ----------------
__global__ void mk_tables(const float* __restrict__ f, float* __restrict__ c, float* __restrict__ s,
                          float* __restrict__ ct, float* __restrict__ st){
  int i = blockIdx.x*256 + threadIdx.x;     // i = t*64 + d
  float v = f[i];
  float cv = cosf(v), sv = sinf(v);
  c[i] = cv;
  s[i] = sv;
  int t = i >> 6, d = i & 63;
  ct[d*T_SEQ + t] = cv;
  st[d*T_SEQ + t] = sv;
}

// ---------------- fp32 -> bf16 elementwise (8/thread) ----------------
__global__ void cvt_bf16(const float* __restrict__ in, u16* __restrict__ out){
  size_t i = (size_t)blockIdx.x*256 + threadIdx.x;
  const float4* p = (const float4*)(in + i*8);
  float4 a = p[0], b = p[1];
  u16x8 o;
  o[0]=f2bf(a.x); o[1]=f2bf(a.y); o[2]=f2bf(a.z); o[3]=f2bf(a.w);
  o[4]=f2bf(b.x); o[5]=f2bf(b.y); o[6]=f2bf(b.z); o[7]=f2bf(b.w);
  *(u16x8*)(out + i*8) = o;
}

// ---------------- W (K x N fp32) -> Wt (N x K bf16), tiled transpose ----------------
__global__ void wtrans(const float* __restrict__ W, u16* __restrict__ Wt, int K, int N){
  __shared__ float t[32][33];
  int tx = threadIdx.x, ty = threadIdx.y;
  int nb = blockIdx.x*32, kb = blockIdx.y*32;
#pragma unroll
  for (int j=0;j<4;j++) t[ty+8*j][tx] = W[(size_t)(kb+ty+8*j)*N + nb + tx];
  __syncthreads();
#pragma unroll
  for (int j=0;j<4;j++) Wt[(size_t)(nb+ty+8*j)*K + kb + tx] = f2bf(t[tx][ty+8*j]);
}

// ---------------- 2-phase GEMM (BM=256, BN templated) — used for KV projection ----------------
template<int BN>
__global__ __launch_bounds__(512, 2) void gemm256(
    const u16* __restrict__ A, const u16* __restrict__ Bt,
    float* __restrict__ C, int N, int K)
{
  constexpr int NGB = BN/64;
  constexpr int NF  = BN/64;
  __shared__ u16 Ab[2][16384];
  __shared__ u16 Bb[2][BN*64];
  const int tid = threadIdx.x;
  const int w = tid >> 6, lane = tid & 63;
  const int lo = lane & 15, hi = lane >> 4;

  const int nbx = N / BN;
  const int cpx = (int)gridDim.x >> 3;
  const int swzb = ((int)blockIdx.x & 7)*cpx + ((int)blockIdx.x >> 3);
  const int bx = swzb % nbx, by = swzb / nbx;
  const int m0 = by << 8, n0 = bx * BN;
  const int wm = w >> 2, wn = w & 3;

  const int rA = tid >> 3;
  const int chg = (tid & 7) ^ (rA & 7);
  const size_t srcoff = (size_t)rA * K + chg*8;
  const u16* Ag = A  + (size_t)m0*K + srcoff;
  const u16* Bg = Bt + (size_t)n0*K + srcoff;
  const int dstc = (w*64)*8;

  f32x4 acc[8][NF];
#pragma unroll
  for (int i=0;i<8;i++)
#pragma unroll
    for (int j=0;j<NF;j++) acc[i][j] = (f32x4){0.f,0.f,0.f,0.f};

  const int NT = K >> 6;
#pragma unroll
  for (int j=0;j<4;j++)   gll16(Ag + (size_t)j*64*K, &Ab[0][j*4096 + dstc]);
#pragma unroll
  for (int j=0;j<NGB;j++) gll16(Bg + (size_t)j*64*K, &Bb[0][j*4096 + dstc]);

  const int sw = lo & 7;
#pragma unroll 1
  for (int t=0; t<NT; ++t){
    const int cur = t & 1;
    if (t > 0){
      asm volatile("s_waitcnt lgkmcnt(0)" ::: "memory");
      __builtin_amdgcn_s_barrier();
    }
    if (t + 1 < NT){
      const int kt = (t+1) << 6;
      const int nxt = cur ^ 1;
#pragma unroll
      for (int j=0;j<4;j++)   gll16(Ag + (size_t)j*64*K + kt, &Ab[nxt][j*4096 + dstc]);
#pragma unroll
      for (int j=0;j<NGB;j++) gll16(Bg + (size_t)j*64*K + kt, &Bb[nxt][j*4096 + dstc]);
      if constexpr (BN == 256){
        asm volatile("s_waitcnt vmcnt(8)" ::: "memory");
      } else {
        asm volatile("s_waitcnt vmcnt(6)" ::: "memory");
      }
    } else {
      asm volatile("s_waitcnt vmcnt(0)" ::: "memory");
    }
    __builtin_amdgcn_s_barrier();
    __builtin_amdgcn_sched_barrier(0);

    const u16* Ac = &Ab[cur][0] + (wm*128)*64;
    const u16* Bc = &Bb[cur][0] + (wn*(BN/4))*64;
    bf16x8 a[4], b[NF];
#pragma unroll
    for (int ks=0; ks<2; ks++){
      const int ch = ((ks*4 + hi) ^ sw) << 3;
#pragma unroll
      for (int g=0; g<NF; g++) b[g] = *(const bf16x8*)(Bc + (g*16 + lo)*64 + ch);
#pragma unroll
      for (int mh=0; mh<2; mh++){
#pragma unroll
        for (int f=0; f<4; f++) a[f] = *(const bf16x8*)(Ac + (mh*64 + f*16 + lo)*64 + ch);
        __builtin_amdgcn_s_setprio(1);
#pragma unroll
        for (int f=0; f<4; f++)
#pragma unroll
          for (int g=0; g<NF; g++)
            acc[mh*4+f][g] = __builtin_amdgcn_mfma_f32_16x16x32_bf16(a[f], b[g], acc[mh*4+f][g], 0, 0, 0);
        __builtin_amdgcn_s_setprio(0);
      }
    }
  }

#pragma unroll
  for (int mh=0; mh<2; mh++)
#pragma unroll
    for (int f=0; f<4; f++)
#pragma unroll
      for (int g=0; g<NF; g++)
#pragma unroll
        for (int r=0; r<4; r++)
          C[(size_t)(m0 + wm*128 + mh*64 + f*16 + hi*4 + r)*N + n0 + wn*(BN/4) + g*16 + lo] = acc[mh*4+f][g][r];
}

// ---------------- 8-phase GEMM v2: one-phase-ahead LDS reads (double operand banks) ----------------
// Phase p's ds_reads are issued INSIDE phase p-1's MFMA cluster (post-barrier, so the
// region is published) and drained by phase p's lgkmcnt(0) — LDS service overlaps MFMA.
// Regions (u16 offs): R0=0, R1=8192, R2=16384, R3=24576; tiles u,u+1 per iteration.
#define RDA(BK, RG, MH) { _Pragma("unroll") for (int f=0; f<4; f++) BK[f] = *(const bf16x8*)(AL + (RG) + La[MH][f]); }
#define RDB(BK, RG)     { _Pragma("unroll") for (int g=0; g<4; g++) BK[g] = *(const bf16x8*)(BL + (RG) + Lb[g]); }
#define STGA8(RG, KO) { gll16(Ag + offs0 + (KO), AL + (RG) + wofs); gll16(Ag + offs1 + (KO), AL + (RG) + 4096 + wofs); }
#define STGB8(RG, KO) { gll16(Bg + offs0 + (KO), BL + (RG) + wofs); gll16(Bg + offs1 + (KO), BL + (RG) + 4096 + wofs); }
#define MFMAB(AB, BB, MH) { _Pragma("unroll") for (int f=0; f<4; f++) _Pragma("unroll") for (int g=0; g<4; g++) \
    acc[(MH)*4+f][g] = __builtin_amdgcn_mfma_f32_16x16x32_bf16(AB[f], BB[g], acc[(MH)*4+f][g], 0, 0, 0); }
#define PH_HEAD() { __builtin_amdgcn_sched_barrier(0); __builtin_amdgcn_s_barrier(); \
    asm volatile("s_waitcnt lgkmcnt(0)" ::: "memory"); __builtin_amdgcn_sched_barrier(0); __builtin_amdgcn_s_setprio(1); }
#define PH_TAIL() { __builtin_amdgcn_s_setprio(0); __builtin_amdgcn_s_barrier(); }

__global__ __launch_bounds__(512, 2) void gemm8p(
    const u16* __restrict__ A, const u16* __restrict__ Bt,
    float* __restrict__ C, int N, int K)
{
  __shared__ u16 AL[32768];
  __shared__ u16 BL[32768];
  const int tid = threadIdx.x;
  const int w = tid >> 6, lane = tid & 63;
  const int lo = lane & 15, hi = lane >> 4;

  const int nbx = N >> 8;
  const int cpx = (int)gridDim.x >> 3;
  const int swzb = ((int)blockIdx.x & 7)*cpx + ((int)blockIdx.x >> 3);
  const int bx = swzb % nbx, by = swzb / nbx;
  const int m0 = by << 8, n0 = bx << 8;
  const int wm = w >> 2, wn = w & 3;

  int La[2][4], Lb[4];
#pragma unroll
  for (int mh=0; mh<2; mh++)
#pragma unroll
    for (int f=0; f<4; f++){
      int row = wm*128 + mh*64 + f*16 + lo;
      int p = row >> 1;
      La[mh][f] = (p*8 + (((row&1)*4 + hi) ^ (p&7)))*8;
    }
#pragma unroll
  for (int g=0; g<4; g++){
    int row = wn*64 + g*16 + lo;
    int p = row >> 1;
    Lb[g] = (p*8 + (((row&1)*4 + hi) ^ (p&7)))*8;
  }

  int offs0, offs1;
  {
    int n = tid;
    int p = n>>3, e = (n&7) ^ (p&7);
    offs0 = (p*2 + (e>>2))*K + (e&3)*8;
    n = 512 + tid;
    p = n>>3; e = (n&7) ^ (p&7);
    offs1 = (p*2 + (e>>2))*K + (e&3)*8;
  }
  const u16* Ag = A  + (size_t)m0*K;
  const u16* Bg = Bt + (size_t)n0*K;
  const int wofs = w*512;

  f32x4 acc[8][4];
#pragma unroll
  for (int i=0;i<8;i++)
#pragma unroll
    for (int j=0;j<4;j++) acc[i][j] = (f32x4){0.f,0.f,0.f,0.f};

  const int NT = K >> 6;
  bf16x8 aA[4], aB[4], bA[4], bB[4];

  // prologue: stage R0(t0k0), R1(t0k1), R2(t1k0); retire R0; pre-issue P0's operands
  STGA8(0, 0)       STGB8(0, 0)
  STGA8(8192, 32)   STGB8(8192, 32)
  STGA8(16384, 64)  STGB8(16384, 64)
  asm volatile("s_waitcnt vmcnt(8)" ::: "memory");
  __builtin_amdgcn_s_barrier();
  RDA(aA, 0, 0) RDB(bA, 0)

#pragma unroll 1
  for (int u = 0; u < NT-2; u += 2){
    const int ku = u*64;
    // P0: MFMA(R0,mh0); issue aB<-R0 mh1
    STGA8(24576, ku+96)
    PH_HEAD() RDA(aB, 0, 1) MFMAB(aA, bA, 0) PH_TAIL()
    // P1: MFMA(R0,mh1); issue aA,bB<-R1
    STGB8(24576, ku+96)
    asm volatile("s_waitcnt vmcnt(8)" ::: "memory");
    PH_HEAD() RDA(aA, 8192, 0) RDB(bB, 8192) MFMAB(aB, bA, 1) PH_TAIL()
    // P2: MFMA(R1,mh0); issue aB<-R1 mh1
    STGA8(0, ku+128)
    PH_HEAD() RDA(aB, 8192, 1) MFMAB(aA, bB, 0) PH_TAIL()
    // P3: MFMA(R1,mh1); issue aA,bA<-R2
    STGB8(0, ku+128)
    asm volatile("s_waitcnt vmcnt(8)" ::: "memory");
    PH_HEAD() RDA(aA, 16384, 0) RDB(bA, 16384) MFMAB(aB, bB, 1) PH_TAIL()
    // P4: MFMA(R2,mh0); issue aB<-R2 mh1
    STGA8(8192, ku+160)
    PH_HEAD() RDA(aB, 16384, 1) MFMAB(aA, bA, 0) PH_TAIL()
    // P5: MFMA(R2,mh1); issue aA,bB<-R3
    STGB8(8192, ku+160)
    asm volatile("s_waitcnt vmcnt(8)" ::: "memory");
    PH_HEAD() RDA(aA, 24576, 0) RDB(bB, 24576) MFMAB(aB, bA, 1) PH_TAIL()
    // P6: MFMA(R3,mh0); issue aB<-R3 mh1
    STGA8(16384, ku+192)
    PH_HEAD() RDA(aB, 24576, 1) MFMAB(aA, bB, 0) PH_TAIL()
    // P7: MFMA(R3,mh1); issue aA,bA<-R0 (tile u+2)
    STGB8(16384, ku+192)
    asm volatile("s_waitcnt vmcnt(8)" ::: "memory");
    PH_HEAD() RDA(aA, 0, 0) RDB(bA, 0) MFMAB(aB, bB, 1) PH_TAIL()
  }

  // tail (tiles NT-2, NT-1): stage only R3; drain vmcnt 8 -> 4 -> 0; no reads at final phase
  {
    const int ku = (NT-2)*64;
    STGA8(24576, ku+96)
    PH_HEAD() RDA(aB, 0, 1) MFMAB(aA, bA, 0) PH_TAIL()
    STGB8(24576, ku+96)
    asm volatile("s_waitcnt vmcnt(8)" ::: "memory");
    PH_HEAD() RDA(aA, 8192, 0) RDB(bB, 8192) MFMAB(aB, bA, 1) PH_TAIL()
    PH_HEAD() RDA(aB, 8192, 1) MFMAB(aA, bB, 0) PH_TAIL()
    asm volatile("s_waitcnt vmcnt(4)" ::: "memory");
    PH_HEAD() RDA(aA, 16384, 0) RDB(bA, 16384) MFMAB(aB, bB, 1) PH_TAIL()
    PH_HEAD() RDA(aB, 16384, 1) MFMAB(aA, bA, 0) PH_TAIL()
    asm volatile("s_waitcnt vmcnt(0)" ::: "memory");
    PH_HEAD() RDA(aA, 24576, 0) RDB(bB, 24576) MFMAB(aB, bA, 1) PH_TAIL()
    PH_HEAD() RDA(aB, 24576, 1) MFMAB(aA, bB, 0) PH_TAIL()
    PH_HEAD() MFMAB(aB, bB, 1) PH_TAIL()
  }

  // epilogue
#pragma unroll
  for (int mh=0; mh<2; mh++)
#pragma unroll
    for (int f=0; f<4; f++)
#pragma unroll
      for (int g=0; g<4; g++)
#pragma unroll
        for (int r=0; r<4; r++)
          C[(size_t)(m0 + wm*128 + mh*64 + f*16 + hi*4 + r)*N + n0 + wn*64 + g*16 + lo] = acc[mh*4+f][g][r];
}

// ---------------- RoPE on K: kvf cols 0..1023 -> kb bf16 (b,kvh,t,d) ----------------
__global__ void rope_k(const float* __restrict__ kvf, const float* __restrict__ c,
                       const float* __restrict__ s, u16* __restrict__ kb){
  const int row = blockIdx.x;
  const int b = row >> 11, t = row & (T_SEQ-1);
  const float* ib = kvf + (size_t)row*2048;
#pragma unroll
  for (int k=0;k<2;k++){
    int p = threadIdx.x + k*256;
    int kvh = p >> 6, i = p & 63;
    float cv = c[t*64+i], sv = s[t*64+i];
    float2 v = *(const float2*)(ib + 2*p);
    float vr = v.x*cv - v.y*sv;
    float vi = v.x*sv + v.y*cv;
    u16* o = kb + ((size_t)(b*N_KVH+kvh)*T_SEQ + t)*HD + 2*i;
    ushort2 ov; ov.x = f2bf(vr); ov.y = f2bf(vi);
    *(ushort2*)o = ov;
  }
}

// ---------------- V: kvf cols 1024..2047 -> vt bf16 (b,kvh,d,t) transposed ----------------
__global__ void vtrans(const float* __restrict__ kvf, u16* __restrict__ vt){
  __shared__ float tl[32][33];
  int tx = threadIdx.x, ty = threadIdx.y;
  int t0 = blockIdx.x*32, d0 = blockIdx.y*32, bh = blockIdx.z;
  int b = bh >> 3, kvh = bh & 7;
#pragma unroll
  for (int j=0;j<4;j++)
    tl[ty+8*j][tx] = kvf[(size_t)(b*T_SEQ + t0+ty+8*j)*2048 + 1024 + kvh*HD + d0 + tx];
  __syncthreads();
#pragma unroll
  for (int j=0;j<4;j++)
    vt[((size_t)bh*HD + d0+ty+8*j)*T_SEQ + t0 + tx] = f2bf(tl[tx][ty+8*j]);
}

// ---------------- flash attention v8b: v6b inner loop + fused Q-RoPE (coalesced tables) ----------------
#define KVB 64
__global__ __launch_bounds__(512) void attn_kernel(
    const float* __restrict__ qf, const float* __restrict__ costT, const float* __restrict__ sintT,
    const u16* __restrict__ kb, const u16* __restrict__ vt, u16* __restrict__ attn)
{
  __shared__ u16 KV[2][2][8192];   // [buf][0]=K 64x128, [buf][1]=V 128x64 (16B-chunk XOR-swizzled)

  const int tid = threadIdx.x;
  const int lane = tid & 63, wid = tid >> 6;
  const int lo = lane & 15, hi = lane >> 4;
  const bool lowhi = (hi < 2);
  const int bp0 = lo + 32*(hi & 1);    // src lane for pa words 0,1
  const int bp1 = bp0 + 16;            // src lane for pa words 2,3
  const int h = blockIdx.y, b = blockIdx.z;
  const int kvh = h >> 2;
  const int qt = b ? (int)blockIdx.x : 7 - (int)blockIdx.x;
  const int q0 = qt*256 + wid*32;
  const int ntiles = (qt+1)*4;

  int koff[2], voff[2];
#pragma unroll
  for (int p=0;p<2;p++){
    int s = p*512 + tid;
    int kr = s >> 4, kch = (s & 15) ^ (kr & 7);
    koff[p] = kr*HD + kch*8;
    int vd = s >> 3, vch = (s & 7) ^ (vd & 7);
    voff[p] = vd*T_SEQ + vch*8;
  }
  const u16* Kg = kb + (size_t)(b*N_KVH + kvh)*T_SEQ*HD;
  const u16* Vg = vt + (size_t)(b*N_KVH + kvh)*HD*T_SEQ;

  // Q fragments with fused RoPE: lane lo <-> q-row q0+mb*16+lo, hi <-> d-chunk.
  bf16x8 qfr[2][4];
#pragma unroll
  for (int mb=0;mb<2;mb++){
    const int t = q0 + mb*16 + lo;
    const float* qrow = qf + (size_t)(b*T_SEQ + t)*4096 + h*HD;
#pragma unroll
    for (int kc=0;kc<4;kc++){
      f32x4 v0 = *(const f32x4*)(qrow + kc*32 + hi*8);
      f32x4 v1 = *(const f32x4*)(qrow + kc*32 + hi*8 + 4);
      union { u32 w[4]; bf16x8 v; } pk;
#pragma unroll
      for (int j=0;j<4;j++){
        int i = kc*16 + hi*4 + j;          // rope pair index within head
        float cv = costT[i*T_SEQ + t], sv = sintT[i*T_SEQ + t];
        float xr = (j<2) ? v0[2*j]   : v1[2*(j-2)];
        float xi = (j<2) ? v0[2*j+1] : v1[2*(j-2)+1];
        float vr = (xr*cv - xi*sv)*QSCALE;
        float vi = (xr*sv + xi*cv)*QSCALE;
        pk.w[j] = ((u32)f2bf(vi) << 16) | (u32)f2bf(vr);
      }
      qfr[mb][kc] = pk.v;
    }
  }

  f32x4 acc[2][8];
#pragma unroll
  for (int mb=0;mb<2;mb++)
#pragma unroll
    for (int nd=0;nd<8;nd++) acc[mb][nd] = (f32x4){0.f,0.f,0.f,0.f};
  float m_[2] = {-3.0e38f, -3.0e38f};
  float l_[2] = {0.f, 0.f};

  // prologue: stage tile 0 -> buf 0
#pragma unroll
  for (int p=0;p<2;p++){
    gll16(Kg + koff[p], (u16*)&KV[0][0][0] + (p*512 + wid*64)*8);
    gll16(Vg + voff[p], (u16*)&KV[0][1][0] + (p*512 + wid*64)*8);
  }

#pragma unroll 1
  for (int st=0; st<ntiles; ++st){
    const int cur = st & 1;
    const int sb = st*KVB;
    if (st > 0){
      asm volatile("s_waitcnt lgkmcnt(0)" ::: "memory");
      __builtin_amdgcn_s_barrier();          // (A) prev tile's LDS reads done everywhere
    }
    if (st + 1 < ntiles){
      const int nxt = cur ^ 1;
      const int nb2 = (st+1)*KVB;
#pragma unroll
      for (int p=0;p<2;p++){
        gll16(Kg + nb2*HD + koff[p], (u16*)&KV[nxt][0][0] + (p*512 + wid*64)*8);
        gll16(Vg + nb2    + voff[p], (u16*)&KV[nxt][1][0] + (p*512 + wid*64)*8);
      }
      asm volatile("s_waitcnt vmcnt(4)" ::: "memory");   // tile st landed, st+1 in flight
    } else {
      asm volatile("s_waitcnt vmcnt(0)" ::: "memory");
    }
    __builtin_amdgcn_s_barrier();            // (B) tile st staged for all waves

    const bool live = (sb <= q0 + 31);
    if (live){
      // ---- swapped QK^T: sc[mb][ns] reg r = S[q=q0+mb*16+lo][k=sb+ns*16+hi*4+r]
      f32x4 sc[2][4];
#pragma unroll
      for (int mb=0;mb<2;mb++)
#pragma unroll
        for (int ns=0;ns<4;ns++) sc[mb][ns] = (f32x4){0.f,0.f,0.f,0.f};
      __builtin_amdgcn_s_setprio(1);
#pragma unroll
      for (int ns=0;ns<4;ns++){
        const int row = ns*16 + lo;
        const u16* klp = (const u16*)&KV[cur][0][0] + row*HD;
        const int sw = row & 7;
        bf16x8 kf[4];
#pragma unroll
        for (int kc=0;kc<4;kc++) kf[kc] = *(const bf16x8*)(klp + (((kc*4+hi)^sw)<<3));
#pragma unroll
        for (int kc=0;kc<4;kc++){
          sc[0][ns] = __builtin_amdgcn_mfma_f32_16x16x32_bf16(kf[kc], qfr[0][kc], sc[0][ns], 0, 0, 0);
          sc[1][ns] = __builtin_amdgcn_mfma_f32_16x16x32_bf16(kf[kc], qfr[1][kc], sc[1][ns], 0, 0, 0);
        }
      }
      __builtin_amdgcn_s_setprio(0);

      if (sb + 63 > q0){                     // diagonal: causal mask
#pragma unroll
        for (int mb=0;mb<2;mb++){
          const int qg = q0 + mb*16 + lo;
#pragma unroll
          for (int ns=0;ns<4;ns++)
#pragma unroll
            for (int r=0;r<4;r++){
              int sg = sb + ns*16 + hi*4 + r;
              if (sg > qg) sc[mb][ns][r] = -3.0e38f;
            }
        }
      }

      // ---- online softmax (exp2 domain, per-lane row) + in-reg P -> pa frags
      bf16x8 pa[2][2];
#pragma unroll
      for (int mb=0;mb<2;mb++){
        float mx = fmaxf(fmaxf(fmaxf(sc[mb][0][0],sc[mb][0][1]),fmaxf(sc[mb][0][2],sc[mb][0][3])),
                   fmaxf(fmaxf(fmaxf(sc[mb][1][0],sc[mb][1][1]),fmaxf(sc[mb][1][2],sc[mb][1][3])),
                         fmaxf(fmaxf(sc[mb][2][0],sc[mb][2][1]),
                               fmaxf(fmaxf(sc[mb][2][2],sc[mb][2][3]),
                                     fmaxf(fmaxf(sc[mb][3][0],sc[mb][3][1]),fmaxf(sc[mb][3][2],sc[mb][3][3]))))));
        mx = fmaxf(mx, __shfl_xor(mx, 16));
        mx = fmaxf(mx, __shfl_xor(mx, 32));
        if (__any(mx > m_[mb] + 8.f)){       // defer-max rescale
          float mn = fmaxf(m_[mb], mx);
          float scal = exp2f(m_[mb] - mn);
          m_[mb] = mn;
          l_[mb] *= scal;
          float srow[4];
#pragma unroll
          for (int r=0;r<4;r++) srow[r] = __shfl(scal, hi*4+r);
#pragma unroll
          for (int nd=0;nd<8;nd++)
#pragma unroll
            for (int r=0;r<4;r++) acc[mb][nd][r] *= srow[r];
        }
        float rs = 0.f;
#pragma unroll
        for (int ns=0;ns<4;ns++)
#pragma unroll
          for (int r=0;r<4;r++){
            sc[mb][ns][r] = exp2f(sc[mb][ns][r] - m_[mb]);
            rs += sc[mb][ns][r];
          }
        rs += __shfl_xor(rs, 16);
        rs += __shfl_xor(rs, 32);
        l_[mb] += rs;

        // redistribute via pure shfl (verified mapping)
#pragma unroll
        for (int k2=0;k2<2;k2++){
          u32 P0 = cvt_pk_bf16(sc[mb][2*k2][0],   sc[mb][2*k2][1]);
          u32 P1 = cvt_pk_bf16(sc[mb][2*k2][2],   sc[mb][2*k2][3]);
          u32 Q0 = cvt_pk_bf16(sc[mb][2*k2+1][0], sc[mb][2*k2+1][1]);
          u32 Q1 = cvt_pk_bf16(sc[mb][2*k2+1][2], sc[mb][2*k2+1][3]);
          u32 pA0 = (u32)__shfl((int)P0, bp0);
          u32 pA1 = (u32)__shfl((int)P1, bp0);
          u32 pA2 = (u32)__shfl((int)P0, bp1);
          u32 pA3 = (u32)__shfl((int)P1, bp1);
          u32 qA0 = (u32)__shfl((int)Q0, bp0);
          u32 qA1 = (u32)__shfl((int)Q1, bp0);
          u32 qA2 = (u32)__shfl((int)Q0, bp1);
          u32 qA3 = (u32)__shfl((int)Q1, bp1);
          union { u32 w[4]; bf16x8 v; } pk;
          pk.w[0] = lowhi ? pA0 : qA0;
          pk.w[1] = lowhi ? pA1 : qA1;
          pk.w[2] = lowhi ? pA2 : qA2;
          pk.w[3] = lowhi ? pA3 : qA3;
          pa[mb][k2] = pk.v;
        }
      }

      // ---- PV: acc += P(32x64) * V(64x128)
      __builtin_amdgcn_s_setprio(1);
#pragma unroll
      for (int nd=0;nd<8;nd++){
        const int d = nd*16 + lo;
        const u16* vlp = (const u16*)&KV[cur][1][0] + d*64;
        const int sw = d & 7;
        bf16x8 vf[2];
#pragma unroll
        for (int k2=0;k2<2;k2++) vf[k2] = *(const bf16x8*)(vlp + (((k2*4+hi)^sw)<<3));
#pragma unroll
        for (int k2=0;k2<2;k2++){
          acc[0][nd] = __builtin_amdgcn_mfma_f32_16x16x32_bf16(pa[0][k2], vf[k2], acc[0][nd], 0, 0, 0);
          acc[1][nd] = __builtin_amdgcn_mfma_f32_16x16x32_bf16(pa[1][k2], vf[k2], acc[1][nd], 0, 0, 0);
        }
      }
      __builtin_amdgcn_s_setprio(0);
    }
  }

  // epilogue: l_ lives at q=lo; acc rows are q=mb*16+hi*4+r -> shfl the inverses
#pragma unroll
  for (int mb=0;mb<2;mb++){
    float inv = 1.f / l_[mb];
    float invr[4];
#pragma unroll
    for (int r=0;r<4;r++) invr[r] = __shfl(inv, hi*4+r);
    u16* ob = attn + (size_t)(b*T_SEQ + q0 + mb*16 + hi*4)*4096 + h*HD;
#pragma unroll
    for (int nd=0;nd<8;nd++)
#pragma unroll
      for (int r=0;r<4;r++)
        ob[(size_t)r*4096 + nd*16 + lo] = f2bf(acc[mb][nd][r]*invr[r]);
  }
}

extern "C" void kernel_launch(void* const* d_in, const int* in_sizes, int n_in,
                              void* d_out, int out_size, void* d_ws, size_t ws_size,
                              hipStream_t stream)
{
  (void)in_sizes; (void)n_in; (void)out_size; (void)ws_size;
  const float* x     = (const float*)d_in[0];
  const float* freqs = (const float*)d_in[1];
  const float* wq    = (const float*)d_in[3];
  const float* wk    = (const float*)d_in[4];
  const float* wv    = (const float*)d_in[5];
  const float* wo    = (const float*)d_in[6];

  char* ws = (char*)d_ws;
  float* cost  = (float*)(ws + 0);            // 512 KB
  float* sint  = (float*)(ws + 524288);       // 512 KB
  u16* xb   = (u16*)(ws + 1048576);           // 33.5 MB
  u16* wqt  = (u16*)(ws + 34603008);          // 33.5 MB (wot aliases later)
  u16* wkt  = (u16*)(ws + 68157440);          // 8.39 MB — dead after KV gemm; costT/sintT alias here
  u16* wvt  = (u16*)(ws + 76546048);          // 8.39 MB
  float* kvf = (float*)(ws + 84934656);       // 33.5 MB KV-proj scratch (fp32)
  u16* kbuf = (u16*)(ws + 118489088);         // 8.39 MB
  u16* vbuf = (u16*)(ws + 126877696);         // 8.39 MB (ends 135266304)
  u16* attnb = xb;
  u16* wot   = wqt;
  float* costT = (float*)(ws + 68157440);     // aliases dead wkt (written after KV gemm)
  float* sintT = (float*)(ws + 68681728);     //   ends 69206016 < 76546048 ✓

  float* qf = (float*)d_out;                  // pre-RoPE Q (fp32), consumed by attn directly

  dim3 tb(32, 8);

  cvt_bf16<<<8192, 256, 0, stream>>>(x, xb);
  wtrans<<<dim3(128,128), tb, 0, stream>>>(wq, wqt, 4096, 4096);
  wtrans<<<dim3(32,128),  tb, 0, stream>>>(wk, wkt, 4096, 1024);
  wtrans<<<dim3(32,128),  tb, 0, stream>>>(wv, wvt, 4096, 1024);

  gemm8p<<<dim3(256), 512, 0, stream>>>(xb, wqt, qf, 4096, 4096);

  gemm256<128><<<dim3(256), 512, 0, stream>>>(xb, wkt, kvf, 2048, 4096);

  // wkt now dead -> safe to write transposed tables over it
  mk_tables<<<512, 256, 0, stream>>>(freqs, cost, sint, costT, sintT);

  rope_k<<<4096, 256, 0, stream>>>(kvf, cost, sint, kbuf);
  vtrans<<<dim3(64,4,16), tb, 0, stream>>>(kvf, vbuf);

  attn_kernel<<<dim3(8,32,2), 512, 0, stream>>>(qf, costT, sintT, kbuf, vbuf, attnb);

  wtrans<<<dim3(128,128), tb, 0, stream>>>(wo, wot, 4096, 4096);
  gemm8p<<<dim3(256), 512, 0, stream>>>(attnb, wot, (float*)d_out, 4096, 4096);
}

// Round 19
// 552.885 us; speedup vs baseline: 1.0080x; 1.0080x over previous
//
#include <hip/hip_runtime.h>
#include <cstdint>
#include <cstddef>

typedef float  f32x4  __attribute__((ext_vector_type(4)));
typedef short  bf16x8 __attribute__((ext_vector_type(8)));
typedef unsigned short u16;
typedef u16    u16x8  __attribute__((ext_vector_type(8)));
typedef unsigned int u32;

#define T_SEQ 2048
#define N_HEADS 32
#define N_KVH 8
#define HD 128
#define QSCALE 0.12751743648963412f   // 1/sqrt(128) * log2(e)

__device__ __forceinline__ u16 f2bf(float f){
  union { float f; unsigned u; } v; v.f = f;
  unsigned u = v.u;
  u += 0x7fffu + ((u >> 16) & 1u);   // RNE truncate
  return (u16)(u >> 16);
}

__device__ __forceinline__ u32 cvt_pk_bf16(float a, float b){
  u32 r;
  asm volatile("v_cvt_pk_bf16_f32 %0, %1, %2" : "=v"(r) : "v"(a), "v"(b));
  return r;  // low16 = bf16(a), high16 = bf16(b)
}

__device__ __forceinline__ void gll16(const void* g, void* l){
  __builtin_amdgcn_global_load_lds((const __attribute__((address_space(1))) void*)g,
                                   (__attribute__((address_space(3))) void*)l, 16, 0, 0);
}

__device__ __forceinline__ u32 lds_addr(const void* p){
  return (u32)(size_t)(__attribute__((address_space(3))) const void*)p;
}

// ---------------- cos/sin tables from freqs (T x 64), plus transposed (64 x T) ----------------
__global__ void mk_tables(const float* __restrict__ f, float* __restrict__ c, float* __restrict__ s,
                          float* __restrict__ ct, float* __restrict__ st){
  int i = blockIdx.x*256 + threadIdx.x;     // i = t*64 + d
  float v = f[i];
  float cv = cosf(v), sv = sinf(v);
  c[i] = cv;
  s[i] = sv;
  int t = i >> 6, d = i & 63;
  ct[d*T_SEQ + t] = cv;
  st[d*T_SEQ + t] = sv;
}

// ---------------- fp32 -> bf16 elementwise (8/thread) ----------------
__global__ void cvt_bf16(const float* __restrict__ in, u16* __restrict__ out){
  size_t i = (size_t)blockIdx.x*256 + threadIdx.x;
  const float4* p = (const float4*)(in + i*8);
  float4 a = p[0], b = p[1];
  u16x8 o;
  o[0]=f2bf(a.x); o[1]=f2bf(a.y); o[2]=f2bf(a.z); o[3]=f2bf(a.w);
  o[4]=f2bf(b.x); o[5]=f2bf(b.y); o[6]=f2bf(b.z); o[7]=f2bf(b.w);
  *(u16x8*)(out + i*8) = o;
}

// ---------------- W (K x N fp32) -> Wt (N x K bf16), tiled transpose ----------------
__global__ void wtrans(const float* __restrict__ W, u16* __restrict__ Wt, int K, int N){
  __shared__ float t[32][33];
  int tx = threadIdx.x, ty = threadIdx.y;
  int nb = blockIdx.x*32, kb = blockIdx.y*32;
#pragma unroll
  for (int j=0;j<4;j++) t[ty+8*j][tx] = W[(size_t)(kb+ty+8*j)*N + nb + tx];
  __syncthreads();
#pragma unroll
  for (int j=0;j<4;j++) Wt[(size_t)(nb+ty+8*j)*K + kb + tx] = f2bf(t[tx][ty+8*j]);
}

// ---------------- 2-phase GEMM (BM=256, BN templated) — used for KV projection ----------------
template<int BN>
__global__ __launch_bounds__(512, 2) void gemm256(
    const u16* __restrict__ A, const u16* __restrict__ Bt,
    float* __restrict__ C, int N, int K)
{
  constexpr int NGB = BN/64;
  constexpr int NF  = BN/64;
  __shared__ u16 Ab[2][16384];
  __shared__ u16 Bb[2][BN*64];
  const int tid = threadIdx.x;
  const int w = tid >> 6, lane = tid & 63;
  const int lo = lane & 15, hi = lane >> 4;

  const int nbx = N / BN;
  const int cpx = (int)gridDim.x >> 3;
  const int swzb = ((int)blockIdx.x & 7)*cpx + ((int)blockIdx.x >> 3);
  const int bx = swzb % nbx, by = swzb / nbx;
  const int m0 = by << 8, n0 = bx * BN;
  const int wm = w >> 2, wn = w & 3;

  const int rA = tid >> 3;
  const int chg = (tid & 7) ^ (rA & 7);
  const size_t srcoff = (size_t)rA * K + chg*8;
  const u16* Ag = A  + (size_t)m0*K + srcoff;
  const u16* Bg = Bt + (size_t)n0*K + srcoff;
  const int dstc = (w*64)*8;

  f32x4 acc[8][NF];
#pragma unroll
  for (int i=0;i<8;i++)
#pragma unroll
    for (int j=0;j<NF;j++) acc[i][j] = (f32x4){0.f,0.f,0.f,0.f};

  const int NT = K >> 6;
#pragma unroll
  for (int j=0;j<4;j++)   gll16(Ag + (size_t)j*64*K, &Ab[0][j*4096 + dstc]);
#pragma unroll
  for (int j=0;j<NGB;j++) gll16(Bg + (size_t)j*64*K, &Bb[0][j*4096 + dstc]);

  const int sw = lo & 7;
#pragma unroll 1
  for (int t=0; t<NT; ++t){
    const int cur = t & 1;
    if (t > 0){
      asm volatile("s_waitcnt lgkmcnt(0)" ::: "memory");
      __builtin_amdgcn_s_barrier();
    }
    if (t + 1 < NT){
      const int kt = (t+1) << 6;
      const int nxt = cur ^ 1;
#pragma unroll
      for (int j=0;j<4;j++)   gll16(Ag + (size_t)j*64*K + kt, &Ab[nxt][j*4096 + dstc]);
#pragma unroll
      for (int j=0;j<NGB;j++) gll16(Bg + (size_t)j*64*K + kt, &Bb[nxt][j*4096 + dstc]);
      if constexpr (BN == 256){
        asm volatile("s_waitcnt vmcnt(8)" ::: "memory");
      } else {
        asm volatile("s_waitcnt vmcnt(6)" ::: "memory");
      }
    } else {
      asm volatile("s_waitcnt vmcnt(0)" ::: "memory");
    }
    __builtin_amdgcn_s_barrier();
    __builtin_amdgcn_sched_barrier(0);

    const u16* Ac = &Ab[cur][0] + (wm*128)*64;
    const u16* Bc = &Bb[cur][0] + (wn*(BN/4))*64;
    bf16x8 a[4], b[NF];
#pragma unroll
    for (int ks=0; ks<2; ks++){
      const int ch = ((ks*4 + hi) ^ sw) << 3;
#pragma unroll
      for (int g=0; g<NF; g++) b[g] = *(const bf16x8*)(Bc + (g*16 + lo)*64 + ch);
#pragma unroll
      for (int mh=0; mh<2; mh++){
#pragma unroll
        for (int f=0; f<4; f++) a[f] = *(const bf16x8*)(Ac + (mh*64 + f*16 + lo)*64 + ch);
        __builtin_amdgcn_s_setprio(1);
#pragma unroll
        for (int f=0; f<4; f++)
#pragma unroll
          for (int g=0; g<NF; g++)
            acc[mh*4+f][g] = __builtin_amdgcn_mfma_f32_16x16x32_bf16(a[f], b[g], acc[mh*4+f][g], 0, 0, 0);
        __builtin_amdgcn_s_setprio(0);
      }
    }
  }

#pragma unroll
  for (int mh=0; mh<2; mh++)
#pragma unroll
    for (int f=0; f<4; f++)
#pragma unroll
      for (int g=0; g<NF; g++)
#pragma unroll
        for (int r=0; r<4; r++)
          C[(size_t)(m0 + wm*128 + mh*64 + f*16 + hi*4 + r)*N + n0 + wn*(BN/4) + g*16 + lo] = acc[mh*4+f][g][r];
}

// ---------------- 8-phase GEMM v3: one-phase-ahead reads via VOLATILE asm ds_read_b128 ----------------
// Read placement is pinned by volatile asm: issued inside phase p-1's MFMA cluster,
// drained (cheaply) by phase p's lgkmcnt(0). Region selected by offset: imm (bytes).
#define RDA(BK, RGS, MH) { _Pragma("unroll") for (int f=0; f<4; f++) \
    asm volatile("ds_read_b128 %0, %1 offset:" RGS : "=v"(BK[f]) : "v"(aAddr[MH][f])); }
#define RDB(BK, RGS) { _Pragma("unroll") for (int g=0; g<4; g++) \
    asm volatile("ds_read_b128 %0, %1 offset:" RGS : "=v"(BK[g]) : "v"(bAddr[g])); }
#define STGA8(RG, KO) { gll16(Ag + offs0 + (KO), AL + (RG) + wofs); gll16(Ag + offs1 + (KO), AL + (RG) + 4096 + wofs); }
#define STGB8(RG, KO) { gll16(Bg + offs0 + (KO), BL + (RG) + wofs); gll16(Bg + offs1 + (KO), BL + (RG) + 4096 + wofs); }
#define MFMAB(AB, BB, MH) { _Pragma("unroll") for (int f=0; f<4; f++) _Pragma("unroll") for (int g=0; g<4; g++) \
    acc[(MH)*4+f][g] = __builtin_amdgcn_mfma_f32_16x16x32_bf16(AB[f], BB[g], acc[(MH)*4+f][g], 0, 0, 0); }
#define PH_HEAD() { __builtin_amdgcn_sched_barrier(0); __builtin_amdgcn_s_barrier(); \
    asm volatile("s_waitcnt lgkmcnt(0)" ::: "memory"); __builtin_amdgcn_sched_barrier(0); __builtin_amdgcn_s_setprio(1); }
#define PH_TAIL() { __builtin_amdgcn_s_setprio(0); __builtin_amdgcn_s_barrier(); }

__global__ __launch_bounds__(512, 2) void gemm8p(
    const u16* __restrict__ A, const u16* __restrict__ Bt,
    float* __restrict__ C, int N, int K)
{
  __shared__ u16 AL[32768];
  __shared__ u16 BL[32768];
  const int tid = threadIdx.x;
  const int w = tid >> 6, lane = tid & 63;
  const int lo = lane & 15, hi = lane >> 4;

  const int nbx = N >> 8;
  const int cpx = (int)gridDim.x >> 3;
  const int swzb = ((int)blockIdx.x & 7)*cpx + ((int)blockIdx.x >> 3);
  const int bx = swzb % nbx, by = swzb / nbx;
  const int m0 = by << 8, n0 = bx << 8;
  const int wm = w >> 2, wn = w & 3;

  // per-lane LDS byte addresses for fragment reads (region added via offset: imm)
  u32 aAddr[2][4], bAddr[4];
#pragma unroll
  for (int mh=0; mh<2; mh++)
#pragma unroll
    for (int f=0; f<4; f++){
      int row = wm*128 + mh*64 + f*16 + lo;
      int p = row >> 1;
      aAddr[mh][f] = lds_addr(AL) + (u32)((p*8 + (((row&1)*4 + hi) ^ (p&7)))*16);
    }
#pragma unroll
  for (int g=0; g<4; g++){
    int row = wn*64 + g*16 + lo;
    int p = row >> 1;
    bAddr[g] = lds_addr(BL) + (u32)((p*8 + (((row&1)*4 + hi) ^ (p&7)))*16);
  }

  int offs0, offs1;
  {
    int n = tid;
    int p = n>>3, e = (n&7) ^ (p&7);
    offs0 = (p*2 + (e>>2))*K + (e&3)*8;
    n = 512 + tid;
    p = n>>3; e = (n&7) ^ (p&7);
    offs1 = (p*2 + (e>>2))*K + (e&3)*8;
  }
  const u16* Ag = A  + (size_t)m0*K;
  const u16* Bg = Bt + (size_t)n0*K;
  const int wofs = w*512;

  f32x4 acc[8][4];
#pragma unroll
  for (int i=0;i<8;i++)
#pragma unroll
    for (int j=0;j<4;j++) acc[i][j] = (f32x4){0.f,0.f,0.f,0.f};

  const int NT = K >> 6;
  bf16x8 aA[4], aB[4], bA[4], bB[4];

  // prologue: stage R0(t0k0), R1(t0k1), R2(t1k0); retire R0; pre-issue P0's operands
  STGA8(0, 0)       STGB8(0, 0)
  STGA8(8192, 32)   STGB8(8192, 32)
  STGA8(16384, 64)  STGB8(16384, 64)
  asm volatile("s_waitcnt vmcnt(8)" ::: "memory");
  __builtin_amdgcn_s_barrier();
  RDA(aA, "0", 0) RDB(bA, "0")

#pragma unroll 1
  for (int u = 0; u < NT-2; u += 2){
    const int ku = u*64;
    // P0: MFMA(R0,mh0); issue aB<-R0 mh1
    STGA8(24576, ku+96)
    PH_HEAD() RDA(aB, "0", 1) MFMAB(aA, bA, 0) PH_TAIL()
    // P1: MFMA(R0,mh1); issue aA,bB<-R1
    STGB8(24576, ku+96)
    asm volatile("s_waitcnt vmcnt(8)" ::: "memory");
    PH_HEAD() RDA(aA, "16384", 0) RDB(bB, "16384") MFMAB(aB, bA, 1) PH_TAIL()
    // P2: MFMA(R1,mh0); issue aB<-R1 mh1
    STGA8(0, ku+128)
    PH_HEAD() RDA(aB, "16384", 1) MFMAB(aA, bB, 0) PH_TAIL()
    // P3: MFMA(R1,mh1); issue aA,bA<-R2
    STGB8(0, ku+128)
    asm volatile("s_waitcnt vmcnt(8)" ::: "memory");
    PH_HEAD() RDA(aA, "32768", 0) RDB(bA, "32768") MFMAB(aB, bB, 1) PH_TAIL()
    // P4: MFMA(R2,mh0); issue aB<-R2 mh1
    STGA8(8192, ku+160)
    PH_HEAD() RDA(aB, "32768", 1) MFMAB(aA, bA, 0) PH_TAIL()
    // P5: MFMA(R2,mh1); issue aA,bB<-R3
    STGB8(8192, ku+160)
    asm volatile("s_waitcnt vmcnt(8)" ::: "memory");
    PH_HEAD() RDA(aA, "49152", 0) RDB(bB, "49152") MFMAB(aB, bA, 1) PH_TAIL()
    // P6: MFMA(R3,mh0); issue aB<-R3 mh1
    STGA8(16384, ku+192)
    PH_HEAD() RDA(aB, "49152", 1) MFMAB(aA, bB, 0) PH_TAIL()
    // P7: MFMA(R3,mh1); issue aA,bA<-R0 (tile u+2)
    STGB8(16384, ku+192)
    asm volatile("s_waitcnt vmcnt(8)" ::: "memory");
    PH_HEAD() RDA(aA, "0", 0) RDB(bA, "0") MFMAB(aB, bB, 1) PH_TAIL()
  }

  // tail (tiles NT-2, NT-1): stage only R3; drain vmcnt 8 -> 4 -> 0; no reads at final phase
  {
    const int ku = (NT-2)*64;
    STGA8(24576, ku+96)
    PH_HEAD() RDA(aB, "0", 1) MFMAB(aA, bA, 0) PH_TAIL()
    STGB8(24576, ku+96)
    asm volatile("s_waitcnt vmcnt(8)" ::: "memory");
    PH_HEAD() RDA(aA, "16384", 0) RDB(bB, "16384") MFMAB(aB, bA, 1) PH_TAIL()
    PH_HEAD() RDA(aB, "16384", 1) MFMAB(aA, bB, 0) PH_TAIL()
    asm volatile("s_waitcnt vmcnt(4)" ::: "memory");
    PH_HEAD() RDA(aA, "32768", 0) RDB(bA, "32768") MFMAB(aB, bB, 1) PH_TAIL()
    PH_HEAD() RDA(aB, "32768", 1) MFMAB(aA, bA, 0) PH_TAIL()
    asm volatile("s_waitcnt vmcnt(0)" ::: "memory");
    PH_HEAD() RDA(aA, "49152", 0) RDB(bB, "49152") MFMAB(aB, bA, 1) PH_TAIL()
    PH_HEAD() RDA(aB, "49152", 1) MFMAB(aA, bB, 0) PH_TAIL()
    PH_HEAD() MFMAB(aB, bB, 1) PH_TAIL()
  }

  // epilogue
#pragma unroll
  for (int mh=0; mh<2; mh++)
#pragma unroll
    for (int f=0; f<4; f++)
#pragma unroll
      for (int g=0; g<4; g++)
#pragma unroll
        for (int r=0; r<4; r++)
          C[(size_t)(m0 + wm*128 + mh*64 + f*16 + hi*4 + r)*N + n0 + wn*64 + g*16 + lo] = acc[mh*4+f][g][r];
}

// ---------------- RoPE on K: kvf cols 0..1023 -> kb bf16 (b,kvh,t,d) ----------------
__global__ void rope_k(const float* __restrict__ kvf, const float* __restrict__ c,
                       const float* __restrict__ s, u16* __restrict__ kb){
  const int row = blockIdx.x;
  const int b = row >> 11, t = row & (T_SEQ-1);
  const float* ib = kvf + (size_t)row*2048;
#pragma unroll
  for (int k=0;k<2;k++){
    int p = threadIdx.x + k*256;
    int kvh = p >> 6, i = p & 63;
    float cv = c[t*64+i], sv = s[t*64+i];
    float2 v = *(const float2*)(ib + 2*p);
    float vr = v.x*cv - v.y*sv;
    float vi = v.x*sv + v.y*cv;
    u16* o = kb + ((size_t)(b*N_KVH+kvh)*T_SEQ + t)*HD + 2*i;
    ushort2 ov; ov.x = f2bf(vr); ov.y = f2bf(vi);
    *(ushort2*)o = ov;
  }
}

// ---------------- V: kvf cols 1024..2047 -> vt bf16 (b,kvh,d,t) transposed ----------------
__global__ void vtrans(const float* __restrict__ kvf, u16* __restrict__ vt){
  __shared__ float tl[32][33];
  int tx = threadIdx.x, ty = threadIdx.y;
  int t0 = blockIdx.x*32, d0 = blockIdx.y*32, bh = blockIdx.z;
  int b = bh >> 3, kvh = bh & 7;
#pragma unroll
  for (int j=0;j<4;j++)
    tl[ty+8*j][tx] = kvf[(size_t)(b*T_SEQ + t0+ty+8*j)*2048 + 1024 + kvh*HD + d0 + tx];
  __syncthreads();
#pragma unroll
  for (int j=0;j<4;j++)
    vt[((size_t)bh*HD + d0+ty+8*j)*T_SEQ + t0 + tx] = f2bf(tl[tx][ty+8*j]);
}

// ---------------- flash attention v8b: v6b inner loop + fused Q-RoPE (coalesced tables) ----------------
#define KVB 64
__global__ __launch_bounds__(512) void attn_kernel(
    const float* __restrict__ qf, const float* __restrict__ costT, const float* __restrict__ sintT,
    const u16* __restrict__ kb, const u16* __restrict__ vt, u16* __restrict__ attn)
{
  __shared__ u16 KV[2][2][8192];   // [buf][0]=K 64x128, [buf][1]=V 128x64 (16B-chunk XOR-swizzled)

  const int tid = threadIdx.x;
  const int lane = tid & 63, wid = tid >> 6;
  const int lo = lane & 15, hi = lane >> 4;
  const bool lowhi = (hi < 2);
  const int bp0 = lo + 32*(hi & 1);    // src lane for pa words 0,1
  const int bp1 = bp0 + 16;            // src lane for pa words 2,3
  const int h = blockIdx.y, b = blockIdx.z;
  const int kvh = h >> 2;
  const int qt = b ? (int)blockIdx.x : 7 - (int)blockIdx.x;
  const int q0 = qt*256 + wid*32;
  const int ntiles = (qt+1)*4;

  int koff[2], voff[2];
#pragma unroll
  for (int p=0;p<2;p++){
    int s = p*512 + tid;
    int kr = s >> 4, kch = (s & 15) ^ (kr & 7);
    koff[p] = kr*HD + kch*8;
    int vd = s >> 3, vch = (s & 7) ^ (vd & 7);
    voff[p] = vd*T_SEQ + vch*8;
  }
  const u16* Kg = kb + (size_t)(b*N_KVH + kvh)*T_SEQ*HD;
  const u16* Vg = vt + (size_t)(b*N_KVH + kvh)*HD*T_SEQ;

  // Q fragments with fused RoPE: lane lo <-> q-row q0+mb*16+lo, hi <-> d-chunk.
  bf16x8 qfr[2][4];
#pragma unroll
  for (int mb=0;mb<2;mb++){
    const int t = q0 + mb*16 + lo;
    const float* qrow = qf + (size_t)(b*T_SEQ + t)*4096 + h*HD;
#pragma unroll
    for (int kc=0;kc<4;kc++){
      f32x4 v0 = *(const f32x4*)(qrow + kc*32 + hi*8);
      f32x4 v1 = *(const f32x4*)(qrow + kc*32 + hi*8 + 4);
      union { u32 w[4]; bf16x8 v; } pk;
#pragma unroll
      for (int j=0;j<4;j++){
        int i = kc*16 + hi*4 + j;          // rope pair index within head
        float cv = costT[i*T_SEQ + t], sv = sintT[i*T_SEQ + t];
        float xr = (j<2) ? v0[2*j]   : v1[2*(j-2)];
        float xi = (j<2) ? v0[2*j+1] : v1[2*(j-2)+1];
        float vr = (xr*cv - xi*sv)*QSCALE;
        float vi = (xr*sv + xi*cv)*QSCALE;
        pk.w[j] = ((u32)f2bf(vi) << 16) | (u32)f2bf(vr);
      }
      qfr[mb][kc] = pk.v;
    }
  }

  f32x4 acc[2][8];
#pragma unroll
  for (int mb=0;mb<2;mb++)
#pragma unroll
    for (int nd=0;nd<8;nd++) acc[mb][nd] = (f32x4){0.f,0.f,0.f,0.f};
  float m_[2] = {-3.0e38f, -3.0e38f};
  float l_[2] = {0.f, 0.f};

  // prologue: stage tile 0 -> buf 0
#pragma unroll
  for (int p=0;p<2;p++){
    gll16(Kg + koff[p], (u16*)&KV[0][0][0] + (p*512 + wid*64)*8);
    gll16(Vg + voff[p], (u16*)&KV[0][1][0] + (p*512 + wid*64)*8);
  }

#pragma unroll 1
  for (int st=0; st<ntiles; ++st){
    const int cur = st & 1;
    const int sb = st*KVB;
    if (st > 0){
      asm volatile("s_waitcnt lgkmcnt(0)" ::: "memory");
      __builtin_amdgcn_s_barrier();          // (A) prev tile's LDS reads done everywhere
    }
    if (st + 1 < ntiles){
      const int nxt = cur ^ 1;
      const int nb2 = (st+1)*KVB;
#pragma unroll
      for (int p=0;p<2;p++){
        gll16(Kg + nb2*HD + koff[p], (u16*)&KV[nxt][0][0] + (p*512 + wid*64)*8);
        gll16(Vg + nb2    + voff[p], (u16*)&KV[nxt][1][0] + (p*512 + wid*64)*8);
      }
      asm volatile("s_waitcnt vmcnt(4)" ::: "memory");   // tile st landed, st+1 in flight
    } else {
      asm volatile("s_waitcnt vmcnt(0)" ::: "memory");
    }
    __builtin_amdgcn_s_barrier();            // (B) tile st staged for all waves

    const bool live = (sb <= q0 + 31);
    if (live){
      // ---- swapped QK^T: sc[mb][ns] reg r = S[q=q0+mb*16+lo][k=sb+ns*16+hi*4+r]
      f32x4 sc[2][4];
#pragma unroll
      for (int mb=0;mb<2;mb++)
#pragma unroll
        for (int ns=0;ns<4;ns++) sc[mb][ns] = (f32x4){0.f,0.f,0.f,0.f};
      __builtin_amdgcn_s_setprio(1);
#pragma unroll
      for (int ns=0;ns<4;ns++){
        const int row = ns*16 + lo;
        const u16* klp = (const u16*)&KV[cur][0][0] + row*HD;
        const int sw = row & 7;
        bf16x8 kf[4];
#pragma unroll
        for (int kc=0;kc<4;kc++) kf[kc] = *(const bf16x8*)(klp + (((kc*4+hi)^sw)<<3));
#pragma unroll
        for (int kc=0;kc<4;kc++){
          sc[0][ns] = __builtin_amdgcn_mfma_f32_16x16x32_bf16(kf[kc], qfr[0][kc], sc[0][ns], 0, 0, 0);
          sc[1][ns] = __builtin_amdgcn_mfma_f32_16x16x32_bf16(kf[kc], qfr[1][kc], sc[1][ns], 0, 0, 0);
        }
      }
      __builtin_amdgcn_s_setprio(0);

      if (sb + 63 > q0){                     // diagonal: causal mask
#pragma unroll
        for (int mb=0;mb<2;mb++){
          const int qg = q0 + mb*16 + lo;
#pragma unroll
          for (int ns=0;ns<4;ns++)
#pragma unroll
            for (int r=0;r<4;r++){
              int sg = sb + ns*16 + hi*4 + r;
              if (sg > qg) sc[mb][ns][r] = -3.0e38f;
            }
        }
      }

      // ---- online softmax (exp2 domain, per-lane row) + in-reg P -> pa frags
      bf16x8 pa[2][2];
#pragma unroll
      for (int mb=0;mb<2;mb++){
        float mx = fmaxf(fmaxf(fmaxf(sc[mb][0][0],sc[mb][0][1]),fmaxf(sc[mb][0][2],sc[mb][0][3])),
                   fmaxf(fmaxf(fmaxf(sc[mb][1][0],sc[mb][1][1]),fmaxf(sc[mb][1][2],sc[mb][1][3])),
                         fmaxf(fmaxf(sc[mb][2][0],sc[mb][2][1]),
                               fmaxf(fmaxf(sc[mb][2][2],sc[mb][2][3]),
                                     fmaxf(fmaxf(sc[mb][3][0],sc[mb][3][1]),fmaxf(sc[mb][3][2],sc[mb][3][3]))))));
        mx = fmaxf(mx, __shfl_xor(mx, 16));
        mx = fmaxf(mx, __shfl_xor(mx, 32));
        if (__any(mx > m_[mb] + 8.f)){       // defer-max rescale
          float mn = fmaxf(m_[mb], mx);
          float scal = exp2f(m_[mb] - mn);
          m_[mb] = mn;
          l_[mb] *= scal;
          float srow[4];
#pragma unroll
          for (int r=0;r<4;r++) srow[r] = __shfl(scal, hi*4+r);
#pragma unroll
          for (int nd=0;nd<8;nd++)
#pragma unroll
            for (int r=0;r<4;r++) acc[mb][nd][r] *= srow[r];
        }
        float rs = 0.f;
#pragma unroll
        for (int ns=0;ns<4;ns++)
#pragma unroll
          for (int r=0;r<4;r++){
            sc[mb][ns][r] = exp2f(sc[mb][ns][r] - m_[mb]);
            rs += sc[mb][ns][r];
          }
        rs += __shfl_xor(rs, 16);
        rs += __shfl_xor(rs, 32);
        l_[mb] += rs;

        // redistribute via pure shfl (verified mapping)
#pragma unroll
        for (int k2=0;k2<2;k2++){
          u32 P0 = cvt_pk_bf16(sc[mb][2*k2][0],   sc[mb][2*k2][1]);
          u32 P1 = cvt_pk_bf16(sc[mb][2*k2][2],   sc[mb][2*k2][3]);
          u32 Q0 = cvt_pk_bf16(sc[mb][2*k2+1][0], sc[mb][2*k2+1][1]);
          u32 Q1 = cvt_pk_bf16(sc[mb][2*k2+1][2], sc[mb][2*k2+1][3]);
          u32 pA0 = (u32)__shfl((int)P0, bp0);
          u32 pA1 = (u32)__shfl((int)P1, bp0);
          u32 pA2 = (u32)__shfl((int)P0, bp1);
          u32 pA3 = (u32)__shfl((int)P1, bp1);
          u32 qA0 = (u32)__shfl((int)Q0, bp0);
          u32 qA1 = (u32)__shfl((int)Q1, bp0);
          u32 qA2 = (u32)__shfl((int)Q0, bp1);
          u32 qA3 = (u32)__shfl((int)Q1, bp1);
          union { u32 w[4]; bf16x8 v; } pk;
          pk.w[0] = lowhi ? pA0 : qA0;
          pk.w[1] = lowhi ? pA1 : qA1;
          pk.w[2] = lowhi ? pA2 : qA2;
          pk.w[3] = lowhi ? pA3 : qA3;
          pa[mb][k2] = pk.v;
        }
      }

      // ---- PV: acc += P(32x64) * V(64x128)
      __builtin_amdgcn_s_setprio(1);
#pragma unroll
      for (int nd=0;nd<8;nd++){
        const int d = nd*16 + lo;
        const u16* vlp = (const u16*)&KV[cur][1][0] + d*64;
        const int sw = d & 7;
        bf16x8 vf[2];
#pragma unroll
        for (int k2=0;k2<2;k2++) vf[k2] = *(const bf16x8*)(vlp + (((k2*4+hi)^sw)<<3));
#pragma unroll
        for (int k2=0;k2<2;k2++){
          acc[0][nd] = __builtin_amdgcn_mfma_f32_16x16x32_bf16(pa[0][k2], vf[k2], acc[0][nd], 0, 0, 0);
          acc[1][nd] = __builtin_amdgcn_mfma_f32_16x16x32_bf16(pa[1][k2], vf[k2], acc[1][nd], 0, 0, 0);
        }
      }
      __builtin_amdgcn_s_setprio(0);
    }
  }

  // epilogue: l_ lives at q=lo; acc rows are q=mb*16+hi*4+r -> shfl the inverses
#pragma unroll
  for (int mb=0;mb<2;mb++){
    float inv = 1.f / l_[mb];
    float invr[4];
#pragma unroll
    for (int r=0;r<4;r++) invr[r] = __shfl(inv, hi*4+r);
    u16* ob = attn + (size_t)(b*T_SEQ + q0 + mb*16 + hi*4)*4096 + h*HD;
#pragma unroll
    for (int nd=0;nd<8;nd++)
#pragma unroll
      for (int r=0;r<4;r++)
        ob[(size_t)r*4096 + nd*16 + lo] = f2bf(acc[mb][nd][r]*invr[r]);
  }
}

extern "C" void kernel_launch(void* const* d_in, const int* in_sizes, int n_in,
                              void* d_out, int out_size, void* d_ws, size_t ws_size,
                              hipStream_t stream)
{
  (void)in_sizes; (void)n_in; (void)out_size; (void)ws_size;
  const float* x     = (const float*)d_in[0];
  const float* freqs = (const float*)d_in[1];
  const float* wq    = (const float*)d_in[3];
  const float* wk    = (const float*)d_in[4];
  const float* wv    = (const float*)d_in[5];
  const float* wo    = (const float*)d_in[6];

  char* ws = (char*)d_ws;
  float* cost  = (float*)(ws + 0);            // 512 KB
  float* sint  = (float*)(ws + 524288);       // 512 KB
  u16* xb   = (u16*)(ws + 1048576);           // 33.5 MB
  u16* wqt  = (u16*)(ws + 34603008);          // 33.5 MB (wot aliases later)
  u16* wkt  = (u16*)(ws + 68157440);          // 8.39 MB — dead after KV gemm; costT/sintT alias here
  u16* wvt  = (u16*)(ws + 76546048);          // 8.39 MB
  float* kvf = (float*)(ws + 84934656);       // 33.5 MB KV-proj scratch (fp32)
  u16* kbuf = (u16*)(ws + 118489088);         // 8.39 MB
  u16* vbuf = (u16*)(ws + 126877696);         // 8.39 MB (ends 135266304)
  u16* attnb = xb;
  u16* wot   = wqt;
  float* costT = (float*)(ws + 68157440);     // aliases dead wkt (written after KV gemm)
  float* sintT = (float*)(ws + 68681728);     //   ends 69206016 < 76546048 ✓

  float* qf = (float*)d_out;                  // pre-RoPE Q (fp32), consumed by attn directly

  dim3 tb(32, 8);

  cvt_bf16<<<8192, 256, 0, stream>>>(x, xb);
  wtrans<<<dim3(128,128), tb, 0, stream>>>(wq, wqt, 4096, 4096);
  wtrans<<<dim3(32,128),  tb, 0, stream>>>(wk, wkt, 4096, 1024);
  wtrans<<<dim3(32,128),  tb, 0, stream>>>(wv, wvt, 4096, 1024);

  gemm8p<<<dim3(256), 512, 0, stream>>>(xb, wqt, qf, 4096, 4096);

  gemm256<128><<<dim3(256), 512, 0, stream>>>(xb, wkt, kvf, 2048, 4096);

  // wkt now dead -> safe to write transposed tables over it
  mk_tables<<<512, 256, 0, stream>>>(freqs, cost, sint, costT, sintT);

  rope_k<<<4096, 256, 0, stream>>>(kvf, cost, sint, kbuf);
  vtrans<<<dim3(64,4,16), tb, 0, stream>>>(kvf, vbuf);

  attn_kernel<<<dim3(8,32,2), 512, 0, stream>>>(qf, costT, sintT, kbuf, vbuf, attnb);

  wtrans<<<dim3(128,128), tb, 0, stream>>>(wo, wot, 4096, 4096);
  gemm8p<<<dim3(256), 512, 0, stream>>>(attnb, wot, (float*)d_out, 4096, 4096);
}